// Round 6
// baseline (226.199 us; speedup 1.0000x reference)
//
#include <hip/hip_runtime.h>

// TranslationLayer: out[b,i,j] = in[b, i+dy[b], j-dx[b]] if in-bounds else 0
// B,H,W,C = 128,512,512,1 fp32. Pure memory-bound shift-gather.
//
// R8: aligned load + DPP funnel. Evidence chain: R5 (2 aligned loads) ==
// R6/R7 (1 unaligned load) == ~64-66us, vs 43us copy floor (m13). A
// 4B-aligned dwordx4 splits in the TA -> both variants issue 2x read-side
// requests; model 43us * (2R+1W)/(1R+1W) = 64.5us matches measurement.
// So: request-issue bound. Fix = ONE aligned dwordx4 (1x requests) and get
// the neighbor group via v_mov_b32_dpp row_shl:1 (VALU pipe: no LDS/lgkm
// wait unlike R1's ds_bpermute funnel, no TA requests unlike R5/R6).
// Lanes (lane&15)==15 sit on a DPP row boundary -> predicated fixup load
// (4 lanes/wave ~= 1 line request, negligible). Combine tree = R5
// (verified); plain store = R7 (NT A/B'd neutral).
// Aligned 4-float groups are fully in- or out-of-range -> group-level
// zero-fill; DPP-shifted v1 inherits the neighbor's zero-masking.

#define TB 128
#define TH 512
#define TW 512
#define W4 (TW / 4)   // 128 float4 groups per row

typedef float f4 __attribute__((ext_vector_type(4)));

__global__ __launch_bounds__(256) void TranslationLayer_63350767616318_kernel(
    const float* __restrict__ in,
    const int*   __restrict__ dx,
    const int*   __restrict__ dy,
    float*       __restrict__ out)
{
    const int tid = threadIdx.x;
    const int b   = blockIdx.x >> 8;                       // 256 blocks/sample
    const int i   = ((blockIdx.x << 1) | (tid >> 7)) & (TH - 1);
    const int j4  = tid & (W4 - 1);

    const int dxb = dx[b];                                  // block-uniform
    const int si  = i + dy[b];                              // wave-uniform row

    f4 res = (f4)(0.f);
    if ((unsigned)si < (unsigned)TH) {                      // wave-uniform
        const f4* __restrict__ row4 =
            (const f4*)in + (size_t)(b * TH + si) * W4;
        const int t = -dxb;
        const int q = t >> 2;     // block-uniform group offset
        const int r = t & 3;      // block-uniform residue
        const int a = j4 + q;     // source group for this lane

        f4 v0 = (f4)(0.f);
        if ((unsigned)a < (unsigned)W4) v0 = row4[a];       // ONE aligned load

        if (r == 0) {
            res = v0;             // shift is a multiple of 4 floats
        } else {
            // v1[i] = v0[i+1] via DPP row_shl:1 (VALU pipe, no TA/DS traffic)
            union { f4 f; int i4[4]; } s, d;
            s.f = v0;
#pragma unroll
            for (int e = 0; e < 4; ++e)
                d.i4[e] = __builtin_amdgcn_update_dpp(
                    0, s.i4[e], 0x101 /*row_shl:1*/, 0xF, 0xF, false);
            f4 v1 = d.f;
            if ((tid & 15) == 15) {      // DPP row boundary: real neighbor
                v1 = (f4)(0.f);
                if ((unsigned)(a + 1) < (unsigned)W4) v1 = row4[a + 1];
            }
            f4 o;
            if (r == 1)      { o.x = v0.y; o.y = v0.z; o.z = v0.w; o.w = v1.x; }
            else if (r == 2) { o.x = v0.z; o.y = v0.w; o.z = v1.x; o.w = v1.y; }
            else             { o.x = v0.w; o.y = v1.x; o.z = v1.y; o.w = v1.z; }
            res = o;
        }
    }
    const int idx = blockIdx.x * 256 + tid;                 // output float4 id
    ((f4*)out)[idx] = res;                                  // plain store (R7)
}

extern "C" void kernel_launch(void* const* d_in, const int* in_sizes, int n_in,
                              void* d_out, int out_size, void* d_ws, size_t ws_size,
                              hipStream_t stream)
{
    const float* in  = (const float*)d_in[0];
    const int*   dx  = (const int*)d_in[1];
    const int*   dy  = (const int*)d_in[2];
    float*       out = (float*)d_out;

    // total float4s = 128*512*128 = 8,388,608 ; /256 threads = 32768 blocks
    const int total4 = TB * TH * W4;
    dim3 grid(total4 / 256), block(256);
    TranslationLayer_63350767616318_kernel<<<grid, block, 0, stream>>>(in, dx, dy, out);
}